// Round 1
// baseline (154.836 us; speedup 1.0000x reference)
//
#include <hip/hip_runtime.h>
#include <stddef.h>

namespace {
constexpr int Hc = 256, Wc = 256, Cc = 64, Bc = 4, Dc = 81;
constexpr int CH = Hc * Wc;  // channel stride in floats
}

// guaranteed-zero 16B region for out-of-range horizontal window loads
__device__ __attribute__((aligned(16))) float g_zero4[4] = {0.f, 0.f, 0.f, 0.f};

// Block = 9 waves (576 threads) = one output row (b,h).
// Wave wi handles vertical offset i = wi-4 (reads x2 row h-i).
// Lane t owns 4 consecutive output pixels w = 4t..4t+3.
// Per channel: 4x float4 global loads, 36 register FMAs (9 horiz offsets x 4 px).
__global__ __launch_bounds__(576)
void corr_softmax_kernel(const float* __restrict__ x1,
                         const float* __restrict__ x2,
                         float* __restrict__ out)
{
    __shared__ float red[9][Wc];  // 9 KB softmax reduction buffer

    const int tid = threadIdx.x;
    const int wi  = tid >> 6;   // 0..8
    const int t   = tid & 63;   // lane
    const int bh  = blockIdx.x; // b*256 + h
    const int b   = bh >> 8;
    const int h   = bh & 255;

    float acc[9][4];
#pragma unroll
    for (int jj = 0; jj < 9; ++jj)
#pragma unroll
        for (int s = 0; s < 4; ++s)
            acc[jj][s] = 0.f;

    const int r = h + 4 - wi;  // x2 row = h - i, with i = wi - 4
    if ((unsigned)r < (unsigned)Hc) {
        const float* x1p = x1 + (size_t)b * Cc * CH + (size_t)h * Wc + 4 * t;
        const float* xr  = x2 + (size_t)b * Cc * CH + (size_t)r * Wc + 4 * t;
        // three aligned float4 loads cover x2 columns [4t-4, 4t+8)
        const float* pA = (t == 0)  ? g_zero4 : (xr - 4);
        const float* pB = xr;
        const float* pC = (t == 63) ? g_zero4 : (xr + 4);
        const ptrdiff_t dA = (t == 0)  ? 0 : CH;
        const ptrdiff_t dC = (t == 63) ? 0 : CH;

#pragma unroll 2
        for (int c = 0; c < Cc; ++c) {
            const float4 p  = *reinterpret_cast<const float4*>(x1p);
            const float4 va = *reinterpret_cast<const float4*>(pA);
            const float4 vb = *reinterpret_cast<const float4*>(pB);
            const float4 vc = *reinterpret_cast<const float4*>(pC);
            const float x2w[12] = {va.x, va.y, va.z, va.w,
                                   vb.x, vb.y, vb.z, vb.w,
                                   vc.x, vc.y, vc.z, vc.w};
            const float pv[4] = {p.x, p.y, p.z, p.w};
            // pixel w=4t+s, horiz offset j=jj-4: x2 col = w-j -> x2w[s-jj+8]
#pragma unroll
            for (int jj = 0; jj < 9; ++jj)
#pragma unroll
                for (int s = 0; s < 4; ++s)
                    acc[jj][s] += pv[s] * x2w[s - jj + 8];
            x1p += CH; pA += dA; pB += CH; pC += dC;
        }
    }

    // ---- softmax over 81 channels, reduced across the 9 waves ----
    // per-wave max of its 9 offsets
    float m0, m1, m2, m3;
    {
        float v0 = acc[0][0], v1 = acc[0][1], v2 = acc[0][2], v3 = acc[0][3];
#pragma unroll
        for (int jj = 1; jj < 9; ++jj) {
            v0 = fmaxf(v0, acc[jj][0]);
            v1 = fmaxf(v1, acc[jj][1]);
            v2 = fmaxf(v2, acc[jj][2]);
            v3 = fmaxf(v3, acc[jj][3]);
        }
        m0 = v0; m1 = v1; m2 = v2; m3 = v3;
    }
    *reinterpret_cast<float4*>(&red[wi][4 * t]) = make_float4(m0, m1, m2, m3);
    __syncthreads();

    float M0, M1, M2, M3;
    {
        float4 q = *reinterpret_cast<const float4*>(&red[0][4 * t]);
        M0 = q.x; M1 = q.y; M2 = q.z; M3 = q.w;
#pragma unroll
        for (int w2 = 1; w2 < 9; ++w2) {
            float4 qq = *reinterpret_cast<const float4*>(&red[w2][4 * t]);
            M0 = fmaxf(M0, qq.x); M1 = fmaxf(M1, qq.y);
            M2 = fmaxf(M2, qq.z); M3 = fmaxf(M3, qq.w);
        }
    }

    // exponentials in-place + per-wave partial sums
    float s0 = 0.f, s1 = 0.f, s2 = 0.f, s3 = 0.f;
#pragma unroll
    for (int jj = 0; jj < 9; ++jj) {
        acc[jj][0] = __expf(acc[jj][0] - M0); s0 += acc[jj][0];
        acc[jj][1] = __expf(acc[jj][1] - M1); s1 += acc[jj][1];
        acc[jj][2] = __expf(acc[jj][2] - M2); s2 += acc[jj][2];
        acc[jj][3] = __expf(acc[jj][3] - M3); s3 += acc[jj][3];
    }
    __syncthreads();  // everyone done reading maxes
    *reinterpret_cast<float4*>(&red[wi][4 * t]) = make_float4(s0, s1, s2, s3);
    __syncthreads();

    float S0, S1, S2, S3;
    {
        float4 q = *reinterpret_cast<const float4*>(&red[0][4 * t]);
        S0 = q.x; S1 = q.y; S2 = q.z; S3 = q.w;
#pragma unroll
        for (int w2 = 1; w2 < 9; ++w2) {
            float4 qq = *reinterpret_cast<const float4*>(&red[w2][4 * t]);
            S0 += qq.x; S1 += qq.y; S2 += qq.z; S3 += qq.w;
        }
    }
    const float i0 = 1.0f / S0, i1 = 1.0f / S1, i2 = 1.0f / S2, i3 = 1.0f / S3;

    // write 9 channels: k = (9*(wi-4) + (jj-4)) mod 81 = 9*wi + jj + 41 (mod 81)
    float* outp = out + (size_t)b * Dc * CH + (size_t)h * Wc + 4 * t;
#pragma unroll
    for (int jj = 0; jj < 9; ++jj) {
        int k = 9 * wi + jj + 41;
        if (k >= 81) k -= 81;
        float4 o = make_float4(acc[jj][0] * i0, acc[jj][1] * i1,
                               acc[jj][2] * i2, acc[jj][3] * i3);
        *reinterpret_cast<float4*>(outp + (size_t)k * CH) = o;
    }
}

extern "C" void kernel_launch(void* const* d_in, const int* in_sizes, int n_in,
                              void* d_out, int out_size, void* d_ws, size_t ws_size,
                              hipStream_t stream) {
    (void)in_sizes; (void)n_in; (void)d_ws; (void)ws_size; (void)out_size;
    const float* x1 = (const float*)d_in[0];
    const float* x2 = (const float*)d_in[1];
    float* out = (float*)d_out;
    dim3 grid(Bc * Hc);   // 1024 blocks: one per (b, h) row
    dim3 block(576);      // 9 waves
    hipLaunchKernelGGL(corr_softmax_kernel, grid, block, 0, stream, x1, x2, out);
}

// Round 2
// 95.859 us; speedup vs baseline: 1.6153x; 1.6153x over previous
//
#include <hip/hip_runtime.h>
#include <stddef.h>

namespace {
constexpr int Hc = 256, Wc = 256, Cc = 64, Bc = 4, Dc = 81;
constexpr int CH = Hc * Wc;  // channel stride in floats
}

// guaranteed-zero 16B region for out-of-range horizontal window loads
__device__ __attribute__((aligned(16))) float g_zero4[4] = {0.f, 0.f, 0.f, 0.f};

// Block = 9 waves (576 threads) = one output row (b,h).
// Wave wi handles vertical offset i = wi-4 (reads x2 row h-i).
// Lane t owns 4 consecutive output pixels w = 4t..4t+3.
// Channel loop is software-pipelined depth-3: 12 float4 loads in flight
// while the 36 FMAs of an older channel retire.
__global__ __launch_bounds__(576)
void corr_softmax_kernel(const float* __restrict__ x1,
                         const float* __restrict__ x2,
                         float* __restrict__ out)
{
    __shared__ float red[9][Wc];  // 9 KB softmax reduction buffer

    const int tid = threadIdx.x;
    const int wi  = tid >> 6;   // 0..8
    const int t   = tid & 63;   // lane
    // XCD-aware swizzle: consecutive (b,h) rows share 8/9 x2 rows; put 128
    // consecutive rows on the same XCD so the reuse hits that XCD's L2.
    const int bid = blockIdx.x;
    const int bh  = (bid & 7) * 128 + (bid >> 3);
    const int b   = bh >> 8;
    const int h   = bh & 255;

    float acc[9][4];
#pragma unroll
    for (int jj = 0; jj < 9; ++jj)
#pragma unroll
        for (int s = 0; s < 4; ++s)
            acc[jj][s] = 0.f;

    const int r = h + 4 - wi;  // x2 row = h - i, with i = wi - 4
    if ((unsigned)r < (unsigned)Hc) {
        const float* x1p = x1 + (size_t)b * Cc * CH + (size_t)h * Wc + 4 * t;
        const float* xr  = x2 + (size_t)b * Cc * CH + (size_t)r * Wc + 4 * t;
        // three aligned float4 loads cover x2 columns [4t-4, 4t+8)
        const float* pA = (t == 0)  ? g_zero4 : (xr - 4);
        const float* pB = xr;
        const float* pC = (t == 63) ? g_zero4 : (xr + 4);
        const ptrdiff_t dA = (t == 0)  ? 0 : CH;
        const ptrdiff_t dC = (t == 63) ? 0 : CH;

#define LOADSET(P, VA, VB, VC) do {                          \
        P  = *reinterpret_cast<const float4*>(x1p);          \
        VA = *reinterpret_cast<const float4*>(pA);           \
        VB = *reinterpret_cast<const float4*>(pB);           \
        VC = *reinterpret_cast<const float4*>(pC);           \
        x1p += CH; pA += dA; pB += CH; pC += dC; } while (0)

#define FMASET(P, VA, VB, VC) do {                                        \
        const float w_[12] = {VA.x, VA.y, VA.z, VA.w,                     \
                              VB.x, VB.y, VB.z, VB.w,                     \
                              VC.x, VC.y, VC.z, VC.w};                    \
        const float pv_[4] = {P.x, P.y, P.z, P.w};                        \
        _Pragma("unroll")                                                 \
        for (int jj = 0; jj < 9; ++jj)                                    \
            _Pragma("unroll")                                             \
            for (int s = 0; s < 4; ++s)                                   \
                acc[jj][s] += pv_[s] * w_[s - jj + 8];                    \
        } while (0)

        float4 p0, a0, b0, c0, p1, a1, b1, c1, p2, a2, b2, c2;
        LOADSET(p0, a0, b0, c0);           // ch 0
        LOADSET(p1, a1, b1, c1);           // ch 1
#pragma unroll 1
        for (int i = 0; i < 20; ++i) {     // channels 3i .. 3i+2
            LOADSET(p2, a2, b2, c2); FMASET(p0, a0, b0, c0);
            LOADSET(p0, a0, b0, c0); FMASET(p1, a1, b1, c1);
            LOADSET(p1, a1, b1, c1); FMASET(p2, a2, b2, c2);
        }
        // loaded: ch 0..61; FMA'd: ch 0..59
        LOADSET(p2, a2, b2, c2);           // ch 62
        FMASET(p0, a0, b0, c0);            // ch 60
        LOADSET(p0, a0, b0, c0);           // ch 63
        FMASET(p1, a1, b1, c1);            // ch 61
        FMASET(p2, a2, b2, c2);            // ch 62
        FMASET(p0, a0, b0, c0);            // ch 63
#undef LOADSET
#undef FMASET
    }

    // ---- softmax over 81 channels, reduced across the 9 waves ----
    float m0, m1, m2, m3;
    {
        float v0 = acc[0][0], v1 = acc[0][1], v2 = acc[0][2], v3 = acc[0][3];
#pragma unroll
        for (int jj = 1; jj < 9; ++jj) {
            v0 = fmaxf(v0, acc[jj][0]);
            v1 = fmaxf(v1, acc[jj][1]);
            v2 = fmaxf(v2, acc[jj][2]);
            v3 = fmaxf(v3, acc[jj][3]);
        }
        m0 = v0; m1 = v1; m2 = v2; m3 = v3;
    }
    *reinterpret_cast<float4*>(&red[wi][4 * t]) = make_float4(m0, m1, m2, m3);
    __syncthreads();

    float M0, M1, M2, M3;
    {
        float4 q = *reinterpret_cast<const float4*>(&red[0][4 * t]);
        M0 = q.x; M1 = q.y; M2 = q.z; M3 = q.w;
#pragma unroll
        for (int w2 = 1; w2 < 9; ++w2) {
            float4 qq = *reinterpret_cast<const float4*>(&red[w2][4 * t]);
            M0 = fmaxf(M0, qq.x); M1 = fmaxf(M1, qq.y);
            M2 = fmaxf(M2, qq.z); M3 = fmaxf(M3, qq.w);
        }
    }

    float s0 = 0.f, s1 = 0.f, s2 = 0.f, s3 = 0.f;
#pragma unroll
    for (int jj = 0; jj < 9; ++jj) {
        acc[jj][0] = __expf(acc[jj][0] - M0); s0 += acc[jj][0];
        acc[jj][1] = __expf(acc[jj][1] - M1); s1 += acc[jj][1];
        acc[jj][2] = __expf(acc[jj][2] - M2); s2 += acc[jj][2];
        acc[jj][3] = __expf(acc[jj][3] - M3); s3 += acc[jj][3];
    }
    __syncthreads();  // everyone done reading maxes
    *reinterpret_cast<float4*>(&red[wi][4 * t]) = make_float4(s0, s1, s2, s3);
    __syncthreads();

    float S0, S1, S2, S3;
    {
        float4 q = *reinterpret_cast<const float4*>(&red[0][4 * t]);
        S0 = q.x; S1 = q.y; S2 = q.z; S3 = q.w;
#pragma unroll
        for (int w2 = 1; w2 < 9; ++w2) {
            float4 qq = *reinterpret_cast<const float4*>(&red[w2][4 * t]);
            S0 += qq.x; S1 += qq.y; S2 += qq.z; S3 += qq.w;
        }
    }
    const float i0 = 1.0f / S0, i1 = 1.0f / S1, i2 = 1.0f / S2, i3 = 1.0f / S3;

    // write 9 channels: k = (9*(wi-4) + (jj-4)) mod 81 = 9*wi + jj + 41 (mod 81)
    float* outp = out + (size_t)b * Dc * CH + (size_t)h * Wc + 4 * t;
#pragma unroll
    for (int jj = 0; jj < 9; ++jj) {
        int k = 9 * wi + jj + 41;
        if (k >= 81) k -= 81;
        float4 o = make_float4(acc[jj][0] * i0, acc[jj][1] * i1,
                               acc[jj][2] * i2, acc[jj][3] * i3);
        *reinterpret_cast<float4*>(outp + (size_t)k * CH) = o;
    }
}

extern "C" void kernel_launch(void* const* d_in, const int* in_sizes, int n_in,
                              void* d_out, int out_size, void* d_ws, size_t ws_size,
                              hipStream_t stream) {
    (void)in_sizes; (void)n_in; (void)d_ws; (void)ws_size; (void)out_size;
    const float* x1 = (const float*)d_in[0];
    const float* x2 = (const float*)d_in[1];
    float* out = (float*)d_out;
    dim3 grid(Bc * Hc);   // 1024 blocks: one per (b, h) row
    dim3 block(576);      // 9 waves
    hipLaunchKernelGGL(corr_softmax_kernel, grid, block, 0, stream, x1, x2, out);
}

// Round 3
// 91.554 us; speedup vs baseline: 1.6912x; 1.0470x over previous
//
#include <hip/hip_runtime.h>
#include <stdint.h>
#include <stddef.h>

namespace {
constexpr int Hc = 256, Wc = 256, Cc = 64, Bc = 4, Dc = 81;
constexpr int CH = Hc * Wc;  // channel stride in floats
}

// async global->LDS, 16B per lane, dest = uniform base + lane*16
#define GLOAD_LDS16(g, l)                                                   \
    __builtin_amdgcn_global_load_lds(                                       \
        (const __attribute__((address_space(1))) void*)(g),                 \
        (__attribute__((address_space(3))) void*)(l), 16, 0, 0)

// 36 FMAs: pixel w=4t+s, offset j=jj-4 -> padded x2 idx 4t + (s-jj+8)
#define FMAS(P, A, Bv, Cv)                                                  \
    do {                                                                    \
        const float w_[12] = {A.x,  A.y,  A.z,  A.w,  Bv.x, Bv.y,           \
                              Bv.z, Bv.w, Cv.x, Cv.y, Cv.z, Cv.w};          \
        const float pv_[4] = {P.x, P.y, P.z, P.w};                          \
        _Pragma("unroll") for (int jj = 0; jj < 9; ++jj)                    \
            _Pragma("unroll") for (int s = 0; s < 4; ++s)                   \
                acc[jj][s] += pv_[s] * w_[s - jj + 8];                      \
    } while (0)

// Pipelined phase: wait for this buffer's DMA + x1 load (issued 4 channels
// ago), read 3 windows from LDS, drain LDS reads, then reuse the buffer for
// channel q+4. vmcnt(6): 8 outstanding pair-ordered ops, clear oldest pair.
#define PHASE_I(q)                                                          \
    do {                                                                    \
        asm volatile("s_waitcnt vmcnt(6)" ::: "memory");                    \
        float4 wa = *(const float4*)&xbuf[wi][q][4 * t];                    \
        float4 wb = *(const float4*)&xbuf[wi][q][4 * t + 4];                \
        float4 wc = *(const float4*)&xbuf[wi][q][4 * t + 8];                \
        float4 pv = p##q;                                                   \
        asm volatile("s_waitcnt lgkmcnt(0)" ::: "memory");                  \
        GLOAD_LDS16(x2p + (size_t)(q + 4) * CH, &xbuf[wi][q][4]);           \
        p##q = *(const float4*)(x1p + (size_t)(q + 4) * CH);                \
        FMAS(pv, wa, wb, wc);                                               \
    } while (0)

#define PHASE_N(q, n)                                                       \
    do {                                                                    \
        asm volatile("s_waitcnt vmcnt(" #n ")" ::: "memory");               \
        float4 wa = *(const float4*)&xbuf[wi][q][4 * t];                    \
        float4 wb = *(const float4*)&xbuf[wi][q][4 * t + 4];                \
        float4 wc = *(const float4*)&xbuf[wi][q][4 * t + 8];                \
        FMAS(p##q, wa, wb, wc);                                             \
    } while (0)

// Block = 9 waves = one output row (b,h). Wave wi: vertical offset i=wi-4
// (x2 row h-i). Lane t: 4 pixels w=4t..4t+3. Per channel: 1 global_load_lds
// (x2 row -> padded LDS buf), 1 x1 float4 load, 3 ds_read_b128 windows,
// 36 FMAs. 4 LDS buffers/wave, prefetch distance 4 channels.
__global__ __launch_bounds__(576, 5)
void corr_softmax_kernel(const float* __restrict__ x1,
                         const float* __restrict__ x2,
                         float* __restrict__ out)
{
    __shared__ float red[9][Wc];        // 9 KB softmax reduction
    __shared__ float xbuf[9][4][264];   // 38 KB: per-wave padded x2 rows

    const int tid = threadIdx.x;
    const int wi  = tid >> 6;   // 0..8
    const int t   = tid & 63;
    // XCD-aware swizzle (kept from R2: FETCH 294->72 MB)
    const int bid = blockIdx.x;
    const int bh  = (bid & 7) * 128 + (bid >> 3);
    const int b   = bh >> 8;
    const int h   = bh & 255;

    float acc[9][4];
#pragma unroll
    for (int jj = 0; jj < 9; ++jj)
#pragma unroll
        for (int s = 0; s < 4; ++s)
            acc[jj][s] = 0.f;

    const int r = h + 4 - wi;  // x2 row = h - i
    if ((unsigned)r < (unsigned)Hc) {
        // zero the 4-float pads on both ends of each buffer
        if (t < 8) {
            const int idx = (t < 4) ? t : (256 + t);  // 0..3 / 260..263
#pragma unroll
            for (int q = 0; q < 4; ++q) xbuf[wi][q][idx] = 0.f;
        }
        asm volatile("s_waitcnt lgkmcnt(0)" ::: "memory");

        const float* x1p = x1 + (size_t)b * Cc * CH + (size_t)h * Wc + 4 * t;
        const float* x2p = x2 + (size_t)b * Cc * CH + (size_t)r * Wc + 4 * t;

        // prologue: stage channels 0..3 as ordered (DMA, x1) pairs
        float4 p0, p1, p2, p3;
        GLOAD_LDS16(x2p + 0 * (size_t)CH, &xbuf[wi][0][4]);
        p0 = *(const float4*)(x1p + 0 * (size_t)CH);
        asm volatile("" ::: "memory");
        GLOAD_LDS16(x2p + 1 * (size_t)CH, &xbuf[wi][1][4]);
        p1 = *(const float4*)(x1p + 1 * (size_t)CH);
        asm volatile("" ::: "memory");
        GLOAD_LDS16(x2p + 2 * (size_t)CH, &xbuf[wi][2][4]);
        p2 = *(const float4*)(x1p + 2 * (size_t)CH);
        asm volatile("" ::: "memory");
        GLOAD_LDS16(x2p + 3 * (size_t)CH, &xbuf[wi][3][4]);
        p3 = *(const float4*)(x1p + 3 * (size_t)CH);

#pragma unroll 1
        for (int it = 0; it < 15; ++it) {   // compute 4it..4it+3, issue +4..+7
            PHASE_I(0);
            PHASE_I(1);
            PHASE_I(2);
            PHASE_I(3);
            x1p += 4 * (size_t)CH;
            x2p += 4 * (size_t)CH;
        }
        // epilogue: channels 60..63, drain
        PHASE_N(0, 6);
        PHASE_N(1, 4);
        PHASE_N(2, 2);
        PHASE_N(3, 0);
    }

    // ---- softmax over 81 channels, reduced across the 9 waves ----
    float m0, m1, m2, m3;
    {
        float v0 = acc[0][0], v1 = acc[0][1], v2 = acc[0][2], v3 = acc[0][3];
#pragma unroll
        for (int jj = 1; jj < 9; ++jj) {
            v0 = fmaxf(v0, acc[jj][0]);
            v1 = fmaxf(v1, acc[jj][1]);
            v2 = fmaxf(v2, acc[jj][2]);
            v3 = fmaxf(v3, acc[jj][3]);
        }
        m0 = v0; m1 = v1; m2 = v2; m3 = v3;
    }
    *reinterpret_cast<float4*>(&red[wi][4 * t]) = make_float4(m0, m1, m2, m3);
    __syncthreads();

    float M0, M1, M2, M3;
    {
        float4 q = *reinterpret_cast<const float4*>(&red[0][4 * t]);
        M0 = q.x; M1 = q.y; M2 = q.z; M3 = q.w;
#pragma unroll
        for (int w2 = 1; w2 < 9; ++w2) {
            float4 qq = *reinterpret_cast<const float4*>(&red[w2][4 * t]);
            M0 = fmaxf(M0, qq.x); M1 = fmaxf(M1, qq.y);
            M2 = fmaxf(M2, qq.z); M3 = fmaxf(M3, qq.w);
        }
    }

    float s0 = 0.f, s1 = 0.f, s2 = 0.f, s3 = 0.f;
#pragma unroll
    for (int jj = 0; jj < 9; ++jj) {
        acc[jj][0] = __expf(acc[jj][0] - M0); s0 += acc[jj][0];
        acc[jj][1] = __expf(acc[jj][1] - M1); s1 += acc[jj][1];
        acc[jj][2] = __expf(acc[jj][2] - M2); s2 += acc[jj][2];
        acc[jj][3] = __expf(acc[jj][3] - M3); s3 += acc[jj][3];
    }
    __syncthreads();  // everyone done reading maxes
    *reinterpret_cast<float4*>(&red[wi][4 * t]) = make_float4(s0, s1, s2, s3);
    __syncthreads();

    float S0, S1, S2, S3;
    {
        float4 q = *reinterpret_cast<const float4*>(&red[0][4 * t]);
        S0 = q.x; S1 = q.y; S2 = q.z; S3 = q.w;
#pragma unroll
        for (int w2 = 1; w2 < 9; ++w2) {
            float4 qq = *reinterpret_cast<const float4*>(&red[w2][4 * t]);
            S0 += qq.x; S1 += qq.y; S2 += qq.z; S3 += qq.w;
        }
    }
    const float i0 = 1.0f / S0, i1 = 1.0f / S1, i2 = 1.0f / S2, i3 = 1.0f / S3;

    // k = (9*(wi-4) + (jj-4)) mod 81 = 9*wi + jj + 41 (mod 81)
    float* outp = out + (size_t)b * Dc * CH + (size_t)h * Wc + 4 * t;
#pragma unroll
    for (int jj = 0; jj < 9; ++jj) {
        int k = 9 * wi + jj + 41;
        if (k >= 81) k -= 81;
        float4 o = make_float4(acc[jj][0] * i0, acc[jj][1] * i1,
                               acc[jj][2] * i2, acc[jj][3] * i3);
        *reinterpret_cast<float4*>(outp + (size_t)k * CH) = o;
    }
}

extern "C" void kernel_launch(void* const* d_in, const int* in_sizes, int n_in,
                              void* d_out, int out_size, void* d_ws, size_t ws_size,
                              hipStream_t stream) {
    (void)in_sizes; (void)n_in; (void)d_ws; (void)ws_size; (void)out_size;
    const float* x1 = (const float*)d_in[0];
    const float* x2 = (const float*)d_in[1];
    float* out = (float*)d_out;
    dim3 grid(Bc * Hc);   // 1024 blocks: one per (b, h) row
    dim3 block(576);      // 9 waves
    hipLaunchKernelGGL(corr_softmax_kernel, grid, block, 0, stream, x1, x2, out);
}